// Round 21
// baseline (811.607 us; speedup 1.0000x reference)
//
#include <hip/hip_runtime.h>
#include <hip/hip_bf16.h>

// Problem constants: B=4, N=2048, DIM=512, H=8, DH=64, ORDER=3, TOPK=64, INNER=512
#define SLOTS 80   // sparse slots per row (64 + tie headroom)

typedef __bf16 bf16x8 __attribute__((ext_vector_type(8)));
typedef float  f32x4  __attribute__((ext_vector_type(4)));
typedef unsigned short u16x8 __attribute__((ext_vector_type(8)));

// ---------------------------------------------------------------------------
// K1/K4: fp32 tiled GEMM with bias. BK=32 (kept from R20: fewer barriers,
// measured neutral-at-worst). Per-output fmaf chain k-ascending 0..K-1.
// ---------------------------------------------------------------------------
__global__ __launch_bounds__(256)
void sgemm_bias(const float* __restrict__ A, const float* __restrict__ Bm,
                const float* __restrict__ bias, float* __restrict__ C,
                int M, int N, int K)
{
    __shared__ float As[32][132];
    __shared__ float Bs[32][132];

    const int t  = threadIdx.x;
    const int tx = t & 15, ty = t >> 4;
    const int bm = blockIdx.y << 7, bn = blockIdx.x << 7;

    const int arow = t >> 3,  ak4 = (t & 7) << 2;
    const int bkr  = t >> 5,  bc4 = (t & 31) << 2;

    float4 pa[4], pb[4];
#pragma unroll
    for (int s = 0; s < 4; ++s) {
        pa[s] = *(const float4*)&A[(size_t)(bm + arow + (s << 5)) * K + ak4];
        pb[s] = *(const float4*)&Bm[(size_t)(bkr + (s << 3)) * N + bn + bc4];
    }

    float acc[8][8] = {};

    for (int k0 = 0; k0 < K; k0 += 32) {
        __syncthreads();
#pragma unroll
        for (int s = 0; s < 4; ++s) {
            const int ar = arow + (s << 5);
            As[ak4 + 0][ar] = pa[s].x;
            As[ak4 + 1][ar] = pa[s].y;
            As[ak4 + 2][ar] = pa[s].z;
            As[ak4 + 3][ar] = pa[s].w;
            *(float4*)&Bs[bkr + (s << 3)][bc4] = pb[s];
        }
        __syncthreads();
        if (k0 + 32 < K) {
#pragma unroll
            for (int s = 0; s < 4; ++s) {
                pa[s] = *(const float4*)&A[(size_t)(bm + arow + (s << 5)) * K + k0 + 32 + ak4];
                pb[s] = *(const float4*)&Bm[(size_t)(k0 + 32 + bkr + (s << 3)) * N + bn + bc4];
            }
        }
#pragma unroll
        for (int kk = 0; kk < 32; ++kk) {
            float4 a0 = *(const float4*)&As[kk][(ty << 3) + 0];
            float4 a1 = *(const float4*)&As[kk][(ty << 3) + 4];
            float4 b0 = *(const float4*)&Bs[kk][(tx << 2)];
            float4 b1 = *(const float4*)&Bs[kk][64 + (tx << 2)];
            float ar[8] = {a0.x, a0.y, a0.z, a0.w, a1.x, a1.y, a1.z, a1.w};
            float br[8] = {b0.x, b0.y, b0.z, b0.w, b1.x, b1.y, b1.z, b1.w};
#pragma unroll
            for (int i = 0; i < 8; ++i)
#pragma unroll
                for (int j = 0; j < 8; ++j)
                    acc[i][j] = fmaf(ar[i], br[j], acc[i][j]);
        }
    }

    float bb[8];
#pragma unroll
    for (int j = 0; j < 4; ++j) {
        bb[j]     = bias[bn + (tx << 2) + j];
        bb[j + 4] = bias[bn + 64 + (tx << 2) + j];
    }
#pragma unroll
    for (int i = 0; i < 8; ++i) {
        const size_t row = (size_t)(bm + (ty << 3) + i);
        float4 o0 = {acc[i][0] + bb[0], acc[i][1] + bb[1], acc[i][2] + bb[2], acc[i][3] + bb[3]};
        float4 o1 = {acc[i][4] + bb[4], acc[i][5] + bb[5], acc[i][6] + bb[6], acc[i][7] + bb[7]};
        *(float4*)&C[row * N + bn + (tx << 2)]      = o0;
        *(float4*)&C[row * N + bn + 64 + (tx << 2)] = o1;
    }
}

// ---------------------------------------------------------------------------
// K1b: exact bf16x3 split, vectorized (unchanged).
// ---------------------------------------------------------------------------
__global__ __launch_bounds__(256)
void qk_split(const float* __restrict__ qkv, unsigned short* __restrict__ qfrag,
              unsigned short* __restrict__ kfrag)
{
    const int gid = blockIdx.x * 256 + threadIdx.x;   // 0 .. 524287
    const int dg = gid & 7;                            // d-group: d = dg*8+j
    const int h  = (gid >> 3) & 7;
    const int n  = (gid >> 6) & 2047;
    const int b  = gid >> 17;
    const int bh = (b << 3) + h;

    const size_t src = ((size_t)(b * 2048 + n)) * 1536 + (h << 6) + (dg << 3);

    const int tb = n >> 4;
    const int c  = n & 15;
    const int ks = dg >> 2;                 // d>>5
    const int ln = c | ((dg & 3) << 4);     // c | ((kk>>3)<<4)
    const size_t base0 = ((((size_t)bh * 128 + tb) * 6 + ks) * 64 + ln) * 8;

#pragma unroll
    for (int qk = 0; qk < 2; ++qk) {
        const float4 x0 = *(const float4*)&qkv[src + (qk ? 512 : 0)];
        const float4 x1 = *(const float4*)&qkv[src + (qk ? 512 : 0) + 4];
        unsigned short* outp = qk ? kfrag : qfrag;
        const float xs[8] = {x0.x, x0.y, x0.z, x0.w, x1.x, x1.y, x1.z, x1.w};
        u16x8 vh, vm, vl;
#pragma unroll
        for (int j = 0; j < 8; ++j) {
            const float x = xs[j];
            __hip_bfloat16 h0 = __float2bfloat16(x);
            const float f0 = __bfloat162float(h0);
            const float r1 = x - f0;
            __hip_bfloat16 h1 = __float2bfloat16(r1);
            const float f1 = __bfloat162float(h1);
            const float r2 = r1 - f1;
            __hip_bfloat16 h2 = __float2bfloat16(r2);
            vh[j] = *(unsigned short*)&h0;
            vm[j] = *(unsigned short*)&h1;
            vl[j] = *(unsigned short*)&h2;
        }
        *(u16x8*)(outp + base0)        = vh;   // hi
        *(u16x8*)(outp + base0 + 1024) = vm;   // mid
        *(u16x8*)(outp + base0 + 2048) = vl;   // lo
    }
}

// ---------------------------------------------------------------------------
// K2: R19's deferred-half-fragment MFMA kernel (unchanged — 347 us proven).
// ---------------------------------------------------------------------------
__global__ __launch_bounds__(512, 4)
void scores_topk(const unsigned short* __restrict__ qfrag,
                 const unsigned short* __restrict__ kfrag,
                 float* __restrict__ svals,
                 unsigned short* __restrict__ sidx, int* __restrict__ scnt)
{
    __shared__ float S[8][2052];   // 65664 B

    const int t    = threadIdx.x;
    const int lane = t & 63;
    const int wid  = t >> 6;                        // 0..7
    const int id   = blockIdx.x;                    // 0..4095
    const int bh   = ((id >> 10) << 3) | (id & 7);  // XCD-affine, bijective
    const int rowblk = (id >> 3) & 127;
    const int r0   = rowblk << 4;                   // block's 16 rows

    const bf16x8* qf = (const bf16x8*)qfrag
                     + (((size_t)bh * 128 + rowblk) * 6) * 64 + lane;
    bf16x8 afr[6];
#pragma unroll
    for (int f = 0; f < 6; ++f) afr[f] = qf[f * 64];

    const bf16x8* kf = (const bf16x8*)kfrag + ((size_t)bh * 128 * 6) * 64 + lane;

    const int slot0 = (lane >> 4) << 1;             // S row-slot for acc[0]
    float def[32];                                  // deferred acc[2],acc[3]

#define STEP(I)                                                                \
    {                                                                          \
        const int ct = ((I) << 3) + wid;                                       \
        const bf16x8* kb = kf + (size_t)ct * 384;                              \
        bf16x8 b0 = kb[0];   bf16x8 b1 = kb[64];  bf16x8 b2 = kb[128];         \
        bf16x8 b3 = kb[192]; bf16x8 b4 = kb[256]; bf16x8 b5 = kb[320];         \
        f32x4 acc = {0.f, 0.f, 0.f, 0.f};                                      \
        acc = __builtin_amdgcn_mfma_f32_16x16x32_bf16(afr[0], b0, acc, 0, 0, 0); \
        acc = __builtin_amdgcn_mfma_f32_16x16x32_bf16(afr[1], b1, acc, 0, 0, 0); \
        acc = __builtin_amdgcn_mfma_f32_16x16x32_bf16(afr[0], b2, acc, 0, 0, 0); \
        acc = __builtin_amdgcn_mfma_f32_16x16x32_bf16(afr[1], b3, acc, 0, 0, 0); \
        acc = __builtin_amdgcn_mfma_f32_16x16x32_bf16(afr[2], b0, acc, 0, 0, 0); \
        acc = __builtin_amdgcn_mfma_f32_16x16x32_bf16(afr[3], b1, acc, 0, 0, 0); \
        acc = __builtin_amdgcn_mfma_f32_16x16x32_bf16(afr[2], b2, acc, 0, 0, 0); \
        acc = __builtin_amdgcn_mfma_f32_16x16x32_bf16(afr[3], b3, acc, 0, 0, 0); \
        acc = __builtin_amdgcn_mfma_f32_16x16x32_bf16(afr[0], b4, acc, 0, 0, 0); \
        acc = __builtin_amdgcn_mfma_f32_16x16x32_bf16(afr[1], b5, acc, 0, 0, 0); \
        acc = __builtin_amdgcn_mfma_f32_16x16x32_bf16(afr[4], b0, acc, 0, 0, 0); \
        acc = __builtin_amdgcn_mfma_f32_16x16x32_bf16(afr[5], b1, acc, 0, 0, 0); \
        const int col = (ct << 4) + (lane & 15);                               \
        S[slot0 + 0][col] = acc[0] * 0.125f;                                   \
        S[slot0 + 1][col] = acc[1] * 0.125f;                                   \
        def[2 * (I)]     = acc[2] * 0.125f;                                    \
        def[2 * (I) + 1] = acc[3] * 0.125f;                                    \
    }

    STEP(0)  STEP(1)  STEP(2)  STEP(3)
    STEP(4)  STEP(5)  STEP(6)  STEP(7)
    STEP(8)  STEP(9)  STEP(10) STEP(11)
    STEP(12) STEP(13) STEP(14) STEP(15)
#undef STEP

    __syncthreads();

    const unsigned long long pre64 = (1ull << lane) - 1ull;

#define PHASEB(ROWOFF)                                                         \
    {                                                                          \
        const int rrow = (((wid >> 1) << 2) | (wid & 1)) + (ROWOFF);           \
        float    fv[32];                                                       \
        unsigned uv[32];                                                       \
        _Pragma("unroll")                                                      \
        for (int m = 0; m < 32; ++m) {                                         \
            const float x = S[wid][lane + (m << 6)];                           \
            fv[m] = x;                                                         \
            const unsigned bx = __float_as_uint(x);                            \
            uv[m] = bx ^ (unsigned)(((int)bx >> 31) | 0x80000000);             \
        }                                                                      \
        unsigned lo = 0;                                                       \
        _Pragma("unroll 1")                                                    \
        for (int bit = 31; bit >= 0; --bit) {                                  \
            const unsigned mid = lo | (1u << bit);                             \
            int c = 0;                                                         \
            _Pragma("unroll")                                                  \
            for (int m = 0; m < 32; ++m)                                       \
                c += __popcll(__ballot(uv[m] >= mid));                         \
            if (c >= 64) {                                                     \
                lo = mid;                                                      \
                if (c == 64) break;                                            \
            }                                                                  \
        }                                                                      \
        unsigned um = 0;                                                       \
        _Pragma("unroll")                                                      \
        for (int m = 0; m < 32; ++m) um = uv[m] > um ? uv[m] : um;             \
        _Pragma("unroll")                                                      \
        for (int off = 1; off < 64; off <<= 1) {                               \
            const unsigned o = (unsigned)__shfl_xor((int)um, off, 64);         \
            um = o > um ? o : um;                                              \
        }                                                                      \
        const unsigned mbm = (um & 0x80000000u) ? (um ^ 0x80000000u) : ~um;    \
        const float Mx = __uint_as_float(mbm);                                 \
        float zs = 0.f;                                                        \
        _Pragma("unroll")                                                      \
        for (int m = 0; m < 32; ++m) {                                         \
            const bool keep = uv[m] >= lo;                                     \
            const float ex = keep ? __expf(fv[m] - Mx) : 0.f;                  \
            fv[m] = ex;                                                        \
            zs += ex;                                                          \
        }                                                                      \
        _Pragma("unroll")                                                      \
        for (int off = 1; off < 64; off <<= 1) zs += __shfl_xor(zs, off, 64);  \
        const float zinv = 1.0f / zs;                                          \
        const size_t grow = (size_t)bh * 2048 + r0 + rrow;                     \
        float* vd           = svals + grow * SLOTS;                            \
        unsigned short* idp = sidx  + grow * SLOTS;                            \
        int base = 0;                                                          \
        _Pragma("unroll")                                                      \
        for (int m = 0; m < 32; ++m) {                                         \
            const bool keep = uv[m] >= lo;                                     \
            unsigned long long ball = __ballot(keep);                          \
            if (keep) {                                                        \
                const int my = base + __popcll(ball & pre64);                  \
                if (my < SLOTS) {                                              \
                    vd[my]  = fv[m] * zinv;                                    \
                    idp[my] = (unsigned short)(lane + (m << 6));               \
                }                                                              \
            }                                                                  \
            base += __popcll(ball);                                            \
        }                                                                      \
        if (lane == 0) scnt[grow] = base < SLOTS ? base : SLOTS;               \
    }

    PHASEB(0)

    __syncthreads();

#pragma unroll
    for (int I = 0; I < 16; ++I) {
        const int col = (((I << 3) + wid) << 4) + (lane & 15);
        S[slot0 + 0][col] = def[2 * I];
        S[slot0 + 1][col] = def[2 * I + 1];
    }
    __syncthreads();

    PHASEB(2)
#undef PHASEB
}

// ---------------------------------------------------------------------------
// K3: sparse attn application, x8 unroll (REVERTED to R19's proven form;
// R20's x16 added 32 VGPRs of staging for no gain) + XCD-affine mapping.
// ---------------------------------------------------------------------------
__global__ __launch_bounds__(256)
void spmm(const float* __restrict__ svals, const unsigned short* __restrict__ sidx,
          const int* __restrict__ scnt, const float* __restrict__ qkv,
          const float* __restrict__ vin, float* __restrict__ vout,
          float* __restrict__ res, const float* __restrict__ alphas_raw, int order)
{
    const int lane = threadIdx.x & 63;
    const int id   = blockIdx.x;                      // 0..16383
    const int bh   = ((id & 7) << 2) | (id >> 12);    // XCD-affine, bijective
    const int nblk = (id >> 3) & 511;
    const int n    = (nblk << 2) + (threadIdx.x >> 6);
    const int gr   = (bh << 11) + n;
    const int b    = bh >> 3,  h = bh & 7;

    const float* vb;
    int stride;
    if (order == 0) { vb = qkv + (size_t)b * 2048 * 1536 + 1024 + (h << 6); stride = 1536; }
    else            { vb = vin + ((size_t)bh << 17);                        stride = 64;   }

    const int cnt = scnt[gr];
    const float* va          = svals + (size_t)gr * SLOTS;
    const unsigned short* ia = sidx  + (size_t)gr * SLOTS;

    float acc = 0.f;
    int j = 0;
    for (; j + 8 <= cnt; j += 8) {
        float a0 = va[j],     a1 = va[j + 1], a2 = va[j + 2], a3 = va[j + 3];
        float a4 = va[j + 4], a5 = va[j + 5], a6 = va[j + 6], a7 = va[j + 7];
        int   i0 = ia[j],     i1 = ia[j + 1], i2 = ia[j + 2], i3 = ia[j + 3];
        int   i4 = ia[j + 4], i5 = ia[j + 5], i6 = ia[j + 6], i7 = ia[j + 7];
        acc += a0 * vb[(size_t)i0 * stride + lane];
        acc += a1 * vb[(size_t)i1 * stride + lane];
        acc += a2 * vb[(size_t)i2 * stride + lane];
        acc += a3 * vb[(size_t)i3 * stride + lane];
        acc += a4 * vb[(size_t)i4 * stride + lane];
        acc += a5 * vb[(size_t)i5 * stride + lane];
        acc += a6 * vb[(size_t)i6 * stride + lane];
        acc += a7 * vb[(size_t)i7 * stride + lane];
    }
    for (; j < cnt; ++j) acc += va[j] * vb[(size_t)ia[j] * stride + lane];

    if (order < 2) vout[((size_t)gr << 6) + lane] = acc;

    float ar    = alphas_raw[(order << 3) + h];
    float alpha = ar * 0.5f * (1.0f + erff(ar * 0.70710678f));  // exact gelu
    size_t ro = ((size_t)b * 2048 + n) * 512 + (h << 6) + lane;
    float av  = alpha * acc;
    if (order == 0) res[ro] = av;
    else            res[ro] += av;
}

// ---------------------------------------------------------------------------
extern "C" void kernel_launch(void* const* d_in, const int* in_sizes, int n_in,
                              void* d_out, int out_size, void* d_ws, size_t ws_size,
                              hipStream_t stream)
{
    const float* x      = (const float*)d_in[0];
    const float* Wqkv   = (const float*)d_in[1];
    const float* bqkv   = (const float*)d_in[2];
    const float* Wout   = (const float*)d_in[3];
    const float* bout   = (const float*)d_in[4];
    const float* alphas = (const float*)d_in[5];
    float* out = (float*)d_out;

    // workspace layout (bytes)
    char* ws = (char*)d_ws;
    float*          qkvb  = (float*)ws;                       // 50331648
    float*          svals = (float*)(ws + 50331648);          // 20971520
    unsigned short* sidxp = (unsigned short*)(ws + 71303168); // 10485760
    int*            scntp = (int*)(ws + 81788928);            // 262144
    // v1/v2/resb region is time-shared with qfrag/kfrag (as R15-R20)
    unsigned short* qfrag = (unsigned short*)(ws + 82051072);
    unsigned short* kfrag = (unsigned short*)(ws + 107216896);
    float*          v1    = (float*)(ws + 82051072);
    float*          v2    = (float*)(ws + 98828288);
    float*          resb  = (float*)(ws + 115605504);
    if (ws_size < 132382720) return;                          // need ~126 MB

    // K1: qkv = x @ Wqkv + bqkv
    sgemm_bias<<<dim3(1536 / 128, 8192 / 128), 256, 0, stream>>>(
        x, Wqkv, bqkv, qkvb, 8192, 1536, 512);

    // K1b: exact bf16x3 split of Q,K into fragment-packed layout (vectorized)
    qk_split<<<2048, 256, 0, stream>>>(qkvb, qfrag, kfrag);

    // K2: MFMA scores -> exact top-64(+ties) -> softmax -> sparse rows
    scores_topk<<<4096, 512, 0, stream>>>(qfrag, kfrag, svals, sidxp, scntp);

    // K3 x3: polynomial filter (sparse A applications) — overwrites q/kfrag
    spmm<<<16384, 256, 0, stream>>>(svals, sidxp, scntp, qkvb, nullptr, v1, resb, alphas, 0);
    spmm<<<16384, 256, 0, stream>>>(svals, sidxp, scntp, qkvb, v1, v2, resb, alphas, 1);
    spmm<<<16384, 256, 0, stream>>>(svals, sidxp, scntp, qkvb, v2, nullptr, resb, alphas, 2);

    // K4: out = res @ Wout + bout
    sgemm_bias<<<dim3(512 / 128, 8192 / 128), 256, 0, stream>>>(
        resb, Wout, bout, out, 8192, 512, 512);
}

// Round 23
// 804.685 us; speedup vs baseline: 1.0086x; 1.0086x over previous
//
#include <hip/hip_runtime.h>
#include <hip/hip_bf16.h>

// Problem constants: B=4, N=2048, DIM=512, H=8, DH=64, ORDER=3, TOPK=64, INNER=512
#define SLOTS 80   // sparse slots per row (64 + tie headroom)

typedef __bf16 bf16x8 __attribute__((ext_vector_type(8)));
typedef float  f32x4  __attribute__((ext_vector_type(4)));
typedef unsigned short u16x8 __attribute__((ext_vector_type(8)));

// ---------------------------------------------------------------------------
// K1/K4: fp32 tiled GEMM with bias. BK=16 (R19's exact form — best measured).
// ---------------------------------------------------------------------------
__global__ __launch_bounds__(256)
void sgemm_bias(const float* __restrict__ A, const float* __restrict__ Bm,
                const float* __restrict__ bias, float* __restrict__ C,
                int M, int N, int K)
{
    __shared__ float As[16][132];
    __shared__ float Bs[16][132];

    const int t  = threadIdx.x;
    const int tx = t & 15, ty = t >> 4;
    const int bm = blockIdx.y << 7, bn = blockIdx.x << 7;

    const int arow = t >> 2,  ak4 = (t & 3) << 2;
    const int bkr  = t >> 5,  bc4 = (t & 31) << 2;

    float4 pa[2], pb[2];
#pragma unroll
    for (int s = 0; s < 2; ++s) {
        pa[s] = *(const float4*)&A[(size_t)(bm + arow + (s << 6)) * K + ak4];
        pb[s] = *(const float4*)&Bm[(size_t)(bkr + (s << 3)) * N + bn + bc4];
    }

    float acc[8][8] = {};

    for (int k0 = 0; k0 < K; k0 += 16) {
        __syncthreads();
#pragma unroll
        for (int s = 0; s < 2; ++s) {
            const int ar = arow + (s << 6);
            As[ak4 + 0][ar] = pa[s].x;
            As[ak4 + 1][ar] = pa[s].y;
            As[ak4 + 2][ar] = pa[s].z;
            As[ak4 + 3][ar] = pa[s].w;
            *(float4*)&Bs[bkr + (s << 3)][bc4] = pb[s];
        }
        __syncthreads();
        if (k0 + 16 < K) {
#pragma unroll
            for (int s = 0; s < 2; ++s) {
                pa[s] = *(const float4*)&A[(size_t)(bm + arow + (s << 6)) * K + k0 + 16 + ak4];
                pb[s] = *(const float4*)&Bm[(size_t)(k0 + 16 + bkr + (s << 3)) * N + bn + bc4];
            }
        }
#pragma unroll
        for (int kk = 0; kk < 16; ++kk) {
            float4 a0 = *(const float4*)&As[kk][(ty << 3) + 0];
            float4 a1 = *(const float4*)&As[kk][(ty << 3) + 4];
            float4 b0 = *(const float4*)&Bs[kk][(tx << 2)];
            float4 b1 = *(const float4*)&Bs[kk][64 + (tx << 2)];
            float ar[8] = {a0.x, a0.y, a0.z, a0.w, a1.x, a1.y, a1.z, a1.w};
            float br[8] = {b0.x, b0.y, b0.z, b0.w, b1.x, b1.y, b1.z, b1.w};
#pragma unroll
            for (int i = 0; i < 8; ++i)
#pragma unroll
                for (int j = 0; j < 8; ++j)
                    acc[i][j] = fmaf(ar[i], br[j], acc[i][j]);
        }
    }

    float bb[8];
#pragma unroll
    for (int j = 0; j < 4; ++j) {
        bb[j]     = bias[bn + (tx << 2) + j];
        bb[j + 4] = bias[bn + 64 + (tx << 2) + j];
    }
#pragma unroll
    for (int i = 0; i < 8; ++i) {
        const size_t row = (size_t)(bm + (ty << 3) + i);
        float4 o0 = {acc[i][0] + bb[0], acc[i][1] + bb[1], acc[i][2] + bb[2], acc[i][3] + bb[3]};
        float4 o1 = {acc[i][4] + bb[4], acc[i][5] + bb[5], acc[i][6] + bb[6], acc[i][7] + bb[7]};
        *(float4*)&C[row * N + bn + (tx << 2)]      = o0;
        *(float4*)&C[row * N + bn + 64 + (tx << 2)] = o1;
    }
}

// ---------------------------------------------------------------------------
// K1b: exact bf16x3 split, vectorized (unchanged).
// ---------------------------------------------------------------------------
__global__ __launch_bounds__(256)
void qk_split(const float* __restrict__ qkv, unsigned short* __restrict__ qfrag,
              unsigned short* __restrict__ kfrag)
{
    const int gid = blockIdx.x * 256 + threadIdx.x;   // 0 .. 524287
    const int dg = gid & 7;                            // d-group: d = dg*8+j
    const int h  = (gid >> 3) & 7;
    const int n  = (gid >> 6) & 2047;
    const int b  = gid >> 17;
    const int bh = (b << 3) + h;

    const size_t src = ((size_t)(b * 2048 + n)) * 1536 + (h << 6) + (dg << 3);

    const int tb = n >> 4;
    const int c  = n & 15;
    const int ks = dg >> 2;                 // d>>5
    const int ln = c | ((dg & 3) << 4);     // c | ((kk>>3)<<4)
    const size_t base0 = ((((size_t)bh * 128 + tb) * 6 + ks) * 64 + ln) * 8;

#pragma unroll
    for (int qk = 0; qk < 2; ++qk) {
        const float4 x0 = *(const float4*)&qkv[src + (qk ? 512 : 0)];
        const float4 x1 = *(const float4*)&qkv[src + (qk ? 512 : 0) + 4];
        unsigned short* outp = qk ? kfrag : qfrag;
        const float xs[8] = {x0.x, x0.y, x0.z, x0.w, x1.x, x1.y, x1.z, x1.w};
        u16x8 vh, vm, vl;
#pragma unroll
        for (int j = 0; j < 8; ++j) {
            const float x = xs[j];
            __hip_bfloat16 h0 = __float2bfloat16(x);
            const float f0 = __bfloat162float(h0);
            const float r1 = x - f0;
            __hip_bfloat16 h1 = __float2bfloat16(r1);
            const float f1 = __bfloat162float(h1);
            const float r2 = r1 - f1;
            __hip_bfloat16 h2 = __float2bfloat16(r2);
            vh[j] = *(unsigned short*)&h0;
            vm[j] = *(unsigned short*)&h1;
            vl[j] = *(unsigned short*)&h2;
        }
        *(u16x8*)(outp + base0)        = vh;   // hi
        *(u16x8*)(outp + base0 + 1024) = vm;   // mid
        *(u16x8*)(outp + base0 + 2048) = vl;   // lo
    }
}

// ---------------------------------------------------------------------------
// K2: R19's deferred-half-fragment MFMA kernel (347-355 us proven).
// ---------------------------------------------------------------------------
__global__ __launch_bounds__(512, 4)
void scores_topk(const unsigned short* __restrict__ qfrag,
                 const unsigned short* __restrict__ kfrag,
                 float* __restrict__ svals,
                 unsigned short* __restrict__ sidx, int* __restrict__ scnt)
{
    __shared__ float S[8][2052];   // 65664 B

    const int t    = threadIdx.x;
    const int lane = t & 63;
    const int wid  = t >> 6;                        // 0..7
    const int id   = blockIdx.x;                    // 0..4095
    const int bh   = ((id >> 10) << 3) | (id & 7);  // XCD-affine, bijective
    const int rowblk = (id >> 3) & 127;
    const int r0   = rowblk << 4;                   // block's 16 rows

    const bf16x8* qf = (const bf16x8*)qfrag
                     + (((size_t)bh * 128 + rowblk) * 6) * 64 + lane;
    bf16x8 afr[6];
#pragma unroll
    for (int f = 0; f < 6; ++f) afr[f] = qf[f * 64];

    const bf16x8* kf = (const bf16x8*)kfrag + ((size_t)bh * 128 * 6) * 64 + lane;

    const int slot0 = (lane >> 4) << 1;             // S row-slot for acc[0]
    float def[32];                                  // deferred acc[2],acc[3]

#define STEP(I)                                                                \
    {                                                                          \
        const int ct = ((I) << 3) + wid;                                       \
        const bf16x8* kb = kf + (size_t)ct * 384;                              \
        bf16x8 b0 = kb[0];   bf16x8 b1 = kb[64];  bf16x8 b2 = kb[128];         \
        bf16x8 b3 = kb[192]; bf16x8 b4 = kb[256]; bf16x8 b5 = kb[320];         \
        f32x4 acc = {0.f, 0.f, 0.f, 0.f};                                      \
        acc = __builtin_amdgcn_mfma_f32_16x16x32_bf16(afr[0], b0, acc, 0, 0, 0); \
        acc = __builtin_amdgcn_mfma_f32_16x16x32_bf16(afr[1], b1, acc, 0, 0, 0); \
        acc = __builtin_amdgcn_mfma_f32_16x16x32_bf16(afr[0], b2, acc, 0, 0, 0); \
        acc = __builtin_amdgcn_mfma_f32_16x16x32_bf16(afr[1], b3, acc, 0, 0, 0); \
        acc = __builtin_amdgcn_mfma_f32_16x16x32_bf16(afr[2], b0, acc, 0, 0, 0); \
        acc = __builtin_amdgcn_mfma_f32_16x16x32_bf16(afr[3], b1, acc, 0, 0, 0); \
        acc = __builtin_amdgcn_mfma_f32_16x16x32_bf16(afr[2], b2, acc, 0, 0, 0); \
        acc = __builtin_amdgcn_mfma_f32_16x16x32_bf16(afr[3], b3, acc, 0, 0, 0); \
        acc = __builtin_amdgcn_mfma_f32_16x16x32_bf16(afr[0], b4, acc, 0, 0, 0); \
        acc = __builtin_amdgcn_mfma_f32_16x16x32_bf16(afr[1], b5, acc, 0, 0, 0); \
        acc = __builtin_amdgcn_mfma_f32_16x16x32_bf16(afr[4], b0, acc, 0, 0, 0); \
        acc = __builtin_amdgcn_mfma_f32_16x16x32_bf16(afr[5], b1, acc, 0, 0, 0); \
        const int col = (ct << 4) + (lane & 15);                               \
        S[slot0 + 0][col] = acc[0] * 0.125f;                                   \
        S[slot0 + 1][col] = acc[1] * 0.125f;                                   \
        def[2 * (I)]     = acc[2] * 0.125f;                                    \
        def[2 * (I) + 1] = acc[3] * 0.125f;                                    \
    }

    STEP(0)  STEP(1)  STEP(2)  STEP(3)
    STEP(4)  STEP(5)  STEP(6)  STEP(7)
    STEP(8)  STEP(9)  STEP(10) STEP(11)
    STEP(12) STEP(13) STEP(14) STEP(15)
#undef STEP

    __syncthreads();

    const unsigned long long pre64 = (1ull << lane) - 1ull;

#define PHASEB(ROWOFF)                                                         \
    {                                                                          \
        const int rrow = (((wid >> 1) << 2) | (wid & 1)) + (ROWOFF);           \
        float    fv[32];                                                       \
        unsigned uv[32];                                                       \
        _Pragma("unroll")                                                      \
        for (int m = 0; m < 32; ++m) {                                         \
            const float x = S[wid][lane + (m << 6)];                           \
            fv[m] = x;                                                         \
            const unsigned bx = __float_as_uint(x);                            \
            uv[m] = bx ^ (unsigned)(((int)bx >> 31) | 0x80000000);             \
        }                                                                      \
        unsigned lo = 0;                                                       \
        _Pragma("unroll 1")                                                    \
        for (int bit = 31; bit >= 0; --bit) {                                  \
            const unsigned mid = lo | (1u << bit);                             \
            int c = 0;                                                         \
            _Pragma("unroll")                                                  \
            for (int m = 0; m < 32; ++m)                                       \
                c += __popcll(__ballot(uv[m] >= mid));                         \
            if (c >= 64) {                                                     \
                lo = mid;                                                      \
                if (c == 64) break;                                            \
            }                                                                  \
        }                                                                      \
        unsigned um = 0;                                                       \
        _Pragma("unroll")                                                      \
        for (int m = 0; m < 32; ++m) um = uv[m] > um ? uv[m] : um;             \
        _Pragma("unroll")                                                      \
        for (int off = 1; off < 64; off <<= 1) {                               \
            const unsigned o = (unsigned)__shfl_xor((int)um, off, 64);         \
            um = o > um ? o : um;                                              \
        }                                                                      \
        const unsigned mbm = (um & 0x80000000u) ? (um ^ 0x80000000u) : ~um;    \
        const float Mx = __uint_as_float(mbm);                                 \
        float zs = 0.f;                                                        \
        _Pragma("unroll")                                                      \
        for (int m = 0; m < 32; ++m) {                                         \
            const bool keep = uv[m] >= lo;                                     \
            const float ex = keep ? __expf(fv[m] - Mx) : 0.f;                  \
            fv[m] = ex;                                                        \
            zs += ex;                                                          \
        }                                                                      \
        _Pragma("unroll")                                                      \
        for (int off = 1; off < 64; off <<= 1) zs += __shfl_xor(zs, off, 64);  \
        const float zinv = 1.0f / zs;                                          \
        const size_t grow = (size_t)bh * 2048 + r0 + rrow;                     \
        float* vd           = svals + grow * SLOTS;                            \
        unsigned short* idp = sidx  + grow * SLOTS;                            \
        int base = 0;                                                          \
        _Pragma("unroll")                                                      \
        for (int m = 0; m < 32; ++m) {                                         \
            const bool keep = uv[m] >= lo;                                     \
            unsigned long long ball = __ballot(keep);                          \
            if (keep) {                                                        \
                const int my = base + __popcll(ball & pre64);                  \
                if (my < SLOTS) {                                              \
                    vd[my]  = fv[m] * zinv;                                    \
                    idp[my] = (unsigned short)(lane + (m << 6));               \
                }                                                              \
            }                                                                  \
            base += __popcll(ball);                                            \
        }                                                                      \
        if (lane == 0) scnt[grow] = base < SLOTS ? base : SLOTS;               \
    }

    PHASEB(0)

    __syncthreads();

#pragma unroll
    for (int I = 0; I < 16; ++I) {
        const int col = (((I << 3) + wid) << 4) + (lane & 15);
        S[slot0 + 0][col] = def[2 * I];
        S[slot0 + 1][col] = def[2 * I + 1];
    }
    __syncthreads();

    PHASEB(2)
#undef PHASEB
}

// ---------------------------------------------------------------------------
// K3: sparse attn application, x8 unroll + XCD-affine (R19's exact form).
// ---------------------------------------------------------------------------
__global__ __launch_bounds__(256)
void spmm(const float* __restrict__ svals, const unsigned short* __restrict__ sidx,
          const int* __restrict__ scnt, const float* __restrict__ qkv,
          const float* __restrict__ vin, float* __restrict__ vout,
          float* __restrict__ res, const float* __restrict__ alphas_raw, int order)
{
    const int lane = threadIdx.x & 63;
    const int id   = blockIdx.x;                      // 0..16383
    const int bh   = ((id & 7) << 2) | (id >> 12);    // XCD-affine, bijective
    const int nblk = (id >> 3) & 511;
    const int n    = (nblk << 2) + (threadIdx.x >> 6);
    const int gr   = (bh << 11) + n;
    const int b    = bh >> 3,  h = bh & 7;

    const float* vb;
    int stride;
    if (order == 0) { vb = qkv + (size_t)b * 2048 * 1536 + 1024 + (h << 6); stride = 1536; }
    else            { vb = vin + ((size_t)bh << 17);                        stride = 64;   }

    const int cnt = scnt[gr];
    const float* va          = svals + (size_t)gr * SLOTS;
    const unsigned short* ia = sidx  + (size_t)gr * SLOTS;

    float acc = 0.f;
    int j = 0;
    for (; j + 8 <= cnt; j += 8) {
        float a0 = va[j],     a1 = va[j + 1], a2 = va[j + 2], a3 = va[j + 3];
        float a4 = va[j + 4], a5 = va[j + 5], a6 = va[j + 6], a7 = va[j + 7];
        int   i0 = ia[j],     i1 = ia[j + 1], i2 = ia[j + 2], i3 = ia[j + 3];
        int   i4 = ia[j + 4], i5 = ia[j + 5], i6 = ia[j + 6], i7 = ia[j + 7];
        acc += a0 * vb[(size_t)i0 * stride + lane];
        acc += a1 * vb[(size_t)i1 * stride + lane];
        acc += a2 * vb[(size_t)i2 * stride + lane];
        acc += a3 * vb[(size_t)i3 * stride + lane];
        acc += a4 * vb[(size_t)i4 * stride + lane];
        acc += a5 * vb[(size_t)i5 * stride + lane];
        acc += a6 * vb[(size_t)i6 * stride + lane];
        acc += a7 * vb[(size_t)i7 * stride + lane];
    }
    for (; j < cnt; ++j) acc += va[j] * vb[(size_t)ia[j] * stride + lane];

    if (order < 2) vout[((size_t)gr << 6) + lane] = acc;

    float ar    = alphas_raw[(order << 3) + h];
    float alpha = ar * 0.5f * (1.0f + erff(ar * 0.70710678f));  // exact gelu
    size_t ro = ((size_t)b * 2048 + n) * 512 + (h << 6) + lane;
    float av  = alpha * acc;
    if (order == 0) res[ro] = av;
    else            res[ro] += av;
}

// ---------------------------------------------------------------------------
extern "C" void kernel_launch(void* const* d_in, const int* in_sizes, int n_in,
                              void* d_out, int out_size, void* d_ws, size_t ws_size,
                              hipStream_t stream)
{
    const float* x      = (const float*)d_in[0];
    const float* Wqkv   = (const float*)d_in[1];
    const float* bqkv   = (const float*)d_in[2];
    const float* Wout   = (const float*)d_in[3];
    const float* bout   = (const float*)d_in[4];
    const float* alphas = (const float*)d_in[5];
    float* out = (float*)d_out;

    // workspace layout (bytes)
    char* ws = (char*)d_ws;
    float*          qkvb  = (float*)ws;                       // 50331648
    float*          svals = (float*)(ws + 50331648);          // 20971520
    unsigned short* sidxp = (unsigned short*)(ws + 71303168); // 10485760
    int*            scntp = (int*)(ws + 81788928);            // 262144
    // v1/v2/resb region is time-shared with qfrag/kfrag (every byte read in
    // a call is written earlier in that same call — deterministic)
    unsigned short* qfrag = (unsigned short*)(ws + 82051072);
    unsigned short* kfrag = (unsigned short*)(ws + 107216896);
    float*          v1    = (float*)(ws + 82051072);
    float*          v2    = (float*)(ws + 98828288);
    float*          resb  = (float*)(ws + 115605504);
    if (ws_size < 132382720) return;                          // need ~126 MB

    // K1: qkv = x @ Wqkv + bqkv
    sgemm_bias<<<dim3(1536 / 128, 8192 / 128), 256, 0, stream>>>(
        x, Wqkv, bqkv, qkvb, 8192, 1536, 512);

    // K1b: exact bf16x3 split of Q,K into fragment-packed layout (vectorized)
    qk_split<<<2048, 256, 0, stream>>>(qkvb, qfrag, kfrag);

    // K2: MFMA scores -> exact top-64(+ties) -> softmax -> sparse rows
    scores_topk<<<4096, 512, 0, stream>>>(qfrag, kfrag, svals, sidxp, scntp);

    // K3 x3: polynomial filter (sparse A applications) — overwrites q/kfrag
    spmm<<<16384, 256, 0, stream>>>(svals, sidxp, scntp, qkvb, nullptr, v1, resb, alphas, 0);
    spmm<<<16384, 256, 0, stream>>>(svals, sidxp, scntp, qkvb, v1, v2, resb, alphas, 1);
    spmm<<<16384, 256, 0, stream>>>(svals, sidxp, scntp, qkvb, v2, nullptr, resb, alphas, 2);

    // K4: out = res @ Wout + bout
    sgemm_bias<<<dim3(512 / 128, 8192 / 128), 256, 0, stream>>>(
        resb, Wout, bout, out, 8192, 512, 512);
}